// Round 1
// baseline (1080.483 us; speedup 1.0000x reference)
//
#include <hip/hip_runtime.h>
#include <math.h>

// NNCLR forward loss, fp32 throughout (no fp32 MFMA on CDNA4; bf16 would flip argmax).
// Pipeline: normalize -> NN argmax GEMM (split-Q partials) -> merge+gather ->
//           4x fused GEMM+online-LSE (split-cols partials) -> merge (+diag) -> loss.
// ws requirement: ~9.5 MB (4 B*D f32 buffers + small partial buffers).

#define B_N 4096
#define Q_N 32768
#define D_N 128
#define BD (B_N * D_N)
#define INV_T 10.0f
#define LDSS 68  // LDS row stride (words) for 64-wide d-half tiles; 68%32=4 -> conflict-free pattern

// ws layout (float offsets)
#define WS_P1N 0
#define WS_P2N BD
#define WS_N1 (2 * BD)
#define WS_N2 (3 * BD)
#define WS_NNVAL (4 * BD)                 // 2*B*8 floats
#define WS_NNIDX (WS_NNVAL + 2 * B_N * 8) // 2*B*8 ints
#define WS_MM (WS_NNIDX + 2 * B_N * 8)    // 4*B*4 floats
#define WS_SS (WS_MM + 4 * B_N * 4)       // 4*B*4 floats

__global__ __launch_bounds__(256) void k_normalize(const float* __restrict__ in1,
                                                   const float* __restrict__ in2,
                                                   float* __restrict__ ws) {
  int t = threadIdx.x;
  int w = t >> 6, l = t & 63;
  int rg = blockIdx.x * 4 + w;  // 0..8191
  int view = rg >> 12;
  int row = rg & (B_N - 1);
  const float* src = view ? in2 : in1;
  float* dst = ws + (view ? WS_P2N : WS_P1N);
  float2 v = *(const float2*)(src + row * D_N + 2 * l);
  float ss = fmaf(v.x, v.x, v.y * v.y);
#pragma unroll
  for (int m = 1; m < 64; m <<= 1) ss += __shfl_xor(ss, m);
  float rn = 1.0f / sqrtf(ss);
  float2 o;
  o.x = v.x * rn;
  o.y = v.y * rn;
  *(float2*)(dst + row * D_N + 2 * l) = o;
}

// ---- NN search: per (row-tile, q-chunk) -> per-row (max,idx) partial ----
__global__ __launch_bounds__(256, 2) void k_nn_gemm(const float* __restrict__ ws,
                                                    const float* __restrict__ queue,
                                                    float* __restrict__ nnval,
                                                    int* __restrict__ nnidx) {
  __shared__ __align__(16) float As[128 * LDSS];
  __shared__ __align__(16) float Bs[128 * LDSS];
  const int t = threadIdx.x;
  const int tr = t & 15, tc = t >> 4;
  const int view = blockIdx.z;
  const int rowBase = blockIdx.x * 128;
  const int qStart = blockIdx.y * 4096;
  const float* A = ws + view * BD + rowBase * D_N;

  float rmax[8];
  int ridx[8];
#pragma unroll
  for (int j = 0; j < 8; ++j) {
    rmax[j] = -3e38f;
    ridx[j] = 0;
  }

  for (int ct = 0; ct < 32; ++ct) {
    const float* Bg = queue + (long)(qStart + ct * 128) * D_N;
    float acc[8][8];
#pragma unroll
    for (int j = 0; j < 8; ++j)
#pragma unroll
      for (int k = 0; k < 8; ++k) acc[j][k] = 0.f;

    for (int dh = 0; dh < 2; ++dh) {
      __syncthreads();
#pragma unroll
      for (int i = 0; i < 8; ++i) {
        int idx = i * 256 + t;
        int r = idx >> 4;
        int c = (idx & 15) << 2;
        *(float4*)(&As[r * LDSS + c]) = *(const float4*)(A + r * D_N + dh * 64 + c);
        *(float4*)(&Bs[r * LDSS + c]) = *(const float4*)(Bg + r * D_N + dh * 64 + c);
      }
      __syncthreads();
#pragma unroll 2
      for (int d0 = 0; d0 < 64; d0 += 4) {
        float4 a[8], b[8];
#pragma unroll
        for (int j = 0; j < 8; ++j) a[j] = *(const float4*)(&As[(tr + 16 * j) * LDSS + d0]);
#pragma unroll
        for (int k = 0; k < 8; ++k) b[k] = *(const float4*)(&Bs[(tc + 16 * k) * LDSS + d0]);
#pragma unroll
        for (int j = 0; j < 8; ++j) {
#pragma unroll
          for (int k = 0; k < 8; ++k) {
            float t0 = acc[j][k];
            t0 = fmaf(a[j].x, b[k].x, t0);
            t0 = fmaf(a[j].y, b[k].y, t0);
            t0 = fmaf(a[j].z, b[k].z, t0);
            t0 = fmaf(a[j].w, b[k].w, t0);
            acc[j][k] = t0;
          }
        }
      }
    }
    // running argmax (q ascending per thread -> strict > keeps first index)
#pragma unroll
    for (int j = 0; j < 8; ++j) {
#pragma unroll
      for (int k = 0; k < 8; ++k) {
        float v = acc[j][k];
        if (v > rmax[j]) {
          rmax[j] = v;
          ridx[j] = qStart + ct * 128 + tc + 16 * k;
        }
      }
    }
  }

  // cross-thread (16 per row) reduce via LDS
  __syncthreads();
  float* vbuf = As;      // 2048 floats used
  int* ibuf = (int*)Bs;  // 2048 ints used
#pragma unroll
  for (int j = 0; j < 8; ++j) {
    vbuf[t * 8 + j] = rmax[j];
    ibuf[t * 8 + j] = ridx[j];
  }
  __syncthreads();
  if (t < 128) {
    int trr = t & 15, j = t >> 4;  // local row = trr + 16*j = t
    float bv = -3e38f;
    int bi = 0x7fffffff;
    for (int c = 0; c < 16; ++c) {
      float v = vbuf[(c * 16 + trr) * 8 + j];
      int i = ibuf[(c * 16 + trr) * 8 + j];
      if (v > bv || (v == bv && i < bi)) {
        bv = v;
        bi = i;
      }
    }
    int grow = rowBase + t;
    nnval[(view * B_N + grow) * 8 + blockIdx.y] = bv;
    nnidx[(view * B_N + grow) * 8 + blockIdx.y] = bi;
  }
}

// ---- merge 8 NN partials, gather neighbour, n = p + (nn - p) (mimic reference fp ops) ----
__global__ __launch_bounds__(256) void k_gather(float* __restrict__ ws,
                                                const float* __restrict__ queue) {
  const float* nnval = ws + WS_NNVAL;
  const int* nnidx = (const int*)(ws + WS_NNIDX);
  int t = threadIdx.x, w = t >> 6, l = t & 63;
  int rg = blockIdx.x * 4 + w;  // 0..8191
  int view = rg >> 12, row = rg & (B_N - 1);
  float v = -3e38f;
  int idx = 0x7fffffff;
  if (l < 8) {
    v = nnval[(view * B_N + row) * 8 + l];
    idx = nnidx[(view * B_N + row) * 8 + l];
  }
#pragma unroll
  for (int m = 1; m < 64; m <<= 1) {
    float ov = __shfl_xor(v, m);
    int oi = __shfl_xor(idx, m);
    if (ov > v || (ov == v && oi < idx)) {
      v = ov;
      idx = oi;
    }
  }
  const float* p = ws + view * BD + row * D_N;
  float* n = ws + (2 + view) * BD + row * D_N;
  float2 pv = *(const float2*)(p + 2 * l);
  float2 qv = *(const float2*)(queue + (long)idx * D_N + 2 * l);
  float2 o;
  o.x = pv.x + (qv.x - pv.x);
  o.y = pv.y + (qv.y - pv.y);
  *(float2*)(n + 2 * l) = o;
}

// ---- fused GEMM + online row-LSE partials: pairs (n1,p2),(p2,n1),(n2,p1),(p1,n2) ----
__global__ __launch_bounds__(256, 2) void k_loss_gemm(const float* __restrict__ ws,
                                                      float* __restrict__ Mm,
                                                      float* __restrict__ Ss) {
  __shared__ __align__(16) float As[128 * LDSS];
  __shared__ __align__(16) float Bs[128 * LDSS];
  const int t = threadIdx.x;
  const int tr = t & 15, tc = t >> 4;
  const int pair = blockIdx.z;
  const int rowBase = blockIdx.x * 128;
  const int colStart = blockIdx.y * 1024;
  const float* p1n = ws + WS_P1N;
  const float* p2n = ws + WS_P2N;
  const float* n1 = ws + WS_N1;
  const float* n2 = ws + WS_N2;
  const float* Ap = pair == 0 ? n1 : pair == 1 ? p2n : pair == 2 ? n2 : p1n;
  const float* Bp = pair == 0 ? p2n : pair == 1 ? n1 : pair == 2 ? p1n : n2;
  const float* A = Ap + rowBase * D_N;

  float m[8], s[8];
#pragma unroll
  for (int j = 0; j < 8; ++j) {
    m[j] = -3e38f;
    s[j] = 0.f;
  }

  for (int ct = 0; ct < 8; ++ct) {
    const float* Bg = Bp + (long)(colStart + ct * 128) * D_N;
    float acc[8][8];
#pragma unroll
    for (int j = 0; j < 8; ++j)
#pragma unroll
      for (int k = 0; k < 8; ++k) acc[j][k] = 0.f;

    for (int dh = 0; dh < 2; ++dh) {
      __syncthreads();
#pragma unroll
      for (int i = 0; i < 8; ++i) {
        int idx = i * 256 + t;
        int r = idx >> 4;
        int c = (idx & 15) << 2;
        *(float4*)(&As[r * LDSS + c]) = *(const float4*)(A + r * D_N + dh * 64 + c);
        *(float4*)(&Bs[r * LDSS + c]) = *(const float4*)(Bg + r * D_N + dh * 64 + c);
      }
      __syncthreads();
#pragma unroll 2
      for (int d0 = 0; d0 < 64; d0 += 4) {
        float4 a[8], b[8];
#pragma unroll
        for (int j = 0; j < 8; ++j) a[j] = *(const float4*)(&As[(tr + 16 * j) * LDSS + d0]);
#pragma unroll
        for (int k = 0; k < 8; ++k) b[k] = *(const float4*)(&Bs[(tc + 16 * k) * LDSS + d0]);
#pragma unroll
        for (int j = 0; j < 8; ++j) {
#pragma unroll
          for (int k = 0; k < 8; ++k) {
            float t0 = acc[j][k];
            t0 = fmaf(a[j].x, b[k].x, t0);
            t0 = fmaf(a[j].y, b[k].y, t0);
            t0 = fmaf(a[j].z, b[k].z, t0);
            t0 = fmaf(a[j].w, b[k].w, t0);
            acc[j][k] = t0;
          }
        }
      }
    }
    // online softmax update per row
#pragma unroll
    for (int j = 0; j < 8; ++j) {
      float tm = acc[j][0];
#pragma unroll
      for (int k = 1; k < 8; ++k) tm = fmaxf(tm, acc[j][k]);
      tm *= INV_T;
      float mn = fmaxf(m[j], tm);
      float ssum = 0.f;
#pragma unroll
      for (int k = 0; k < 8; ++k) ssum += __expf(acc[j][k] * INV_T - mn);
      s[j] = fmaf(s[j], __expf(m[j] - mn), ssum);
      m[j] = mn;
    }
  }

  __syncthreads();
  float* mbuf = As;
  float* sbuf = Bs;
#pragma unroll
  for (int j = 0; j < 8; ++j) {
    mbuf[t * 8 + j] = m[j];
    sbuf[t * 8 + j] = s[j];
  }
  __syncthreads();
  if (t < 128) {
    int trr = t & 15, j = t >> 4;
    float M = -3e38f;
    for (int c = 0; c < 16; ++c) M = fmaxf(M, mbuf[(c * 16 + trr) * 8 + j]);
    float S = 0.f;
    for (int c = 0; c < 16; ++c)
      S += sbuf[(c * 16 + trr) * 8 + j] * __expf(mbuf[(c * 16 + trr) * 8 + j] - M);
    int grow = rowBase + t;
    Mm[(pair * B_N + grow) * 4 + blockIdx.y] = M;
    Ss[(pair * B_N + grow) * 4 + blockIdx.y] = S;
  }
}

// ---- final: combine 4 LSE partials, compute diag, write loss ----
__global__ __launch_bounds__(256) void k_merge(const float* __restrict__ ws,
                                               float* __restrict__ out) {
  int t = threadIdx.x, w = t >> 6, l = t & 63;
  int g = blockIdx.x * 4 + w;  // 0..16383
  int pair = g >> 12, row = g & (B_N - 1);
  const float* p1n = ws + WS_P1N;
  const float* p2n = ws + WS_P2N;
  const float* n1 = ws + WS_N1;
  const float* n2 = ws + WS_N2;
  const float* Ap = pair == 0 ? n1 : pair == 1 ? p2n : pair == 2 ? n2 : p1n;
  const float* Bp = pair == 0 ? p2n : pair == 1 ? n1 : pair == 2 ? p1n : n2;
  const float* a = Ap + row * D_N;
  const float* b = Bp + row * D_N;
  float2 av = *(const float2*)(a + 2 * l);
  float2 bv = *(const float2*)(b + 2 * l);
  float dsum = fmaf(av.x, bv.x, av.y * bv.y);
#pragma unroll
  for (int mk = 1; mk < 64; mk <<= 1) dsum += __shfl_xor(dsum, mk);
  float diag = dsum * INV_T;

  const float* Mm = ws + WS_MM;
  const float* Ss = ws + WS_SS;
  float mv = -3e38f, sv = 0.f;
  if (l < 4) {
    mv = Mm[(pair * B_N + row) * 4 + l];
    sv = Ss[(pair * B_N + row) * 4 + l];
  }
#pragma unroll
  for (int mk = 1; mk < 64; mk <<= 1) {
    float om = __shfl_xor(mv, mk);
    float os = __shfl_xor(sv, mk);
    float mn = fmaxf(mv, om);
    sv = sv * __expf(mv - mn) + os * __expf(om - mn);
    mv = mn;
  }
  if (l == 0) out[pair * B_N + row] = mv + logf(sv) - diag;
}

extern "C" void kernel_launch(void* const* d_in, const int* in_sizes, int n_in,
                              void* d_out, int out_size, void* d_ws, size_t ws_size,
                              hipStream_t stream) {
  const float* in1 = (const float*)d_in[0];
  const float* in2 = (const float*)d_in[1];
  const float* queue = (const float*)d_in[2];
  float* out = (float*)d_out;
  float* ws = (float*)d_ws;
  float* nnval = ws + WS_NNVAL;
  int* nnidx = (int*)(ws + WS_NNIDX);
  float* Mm = ws + WS_MM;
  float* Ss = ws + WS_SS;

  hipLaunchKernelGGL(k_normalize, dim3(2048), dim3(256), 0, stream, in1, in2, ws);
  hipLaunchKernelGGL(k_nn_gemm, dim3(32, 8, 2), dim3(256), 0, stream, ws, queue, nnval, nnidx);
  hipLaunchKernelGGL(k_gather, dim3(2048), dim3(256), 0, stream, ws, queue);
  hipLaunchKernelGGL(k_loss_gemm, dim3(32, 4, 4), dim3(256), 0, stream, ws, Mm, Ss);
  hipLaunchKernelGGL(k_merge, dim3(4096), dim3(256), 0, stream, ws, out);
}

// Round 3
// 437.820 us; speedup vs baseline: 2.4679x; 2.4679x over previous
//
#include <hip/hip_runtime.h>
#include <math.h>

// NNCLR forward loss via fp16 MFMA + deterministic fp32 rescore.
// normalize -> k_nn (fp16 MFMA per-64q-tile maxes, no LDS/barriers) ->
// k_rowmax -> k_rescore (exact fp32 argmax over candidate tiles, atomicMax) ->
// k_gather (n = p+(nn-p) fp32, fp16 copy, exact diag) ->
// k_loss (fp16 MFMA + fixed-shift LSE partials) -> k_merge.

#define B_N 4096
#define D_N 128
#define NP 8192    // 2*B p-rows
#define NTILE 512  // 64-wide q tiles (32768/64)
#define INV_T 10.0f
#define C1F (10.0f * 1.4426950408889634f)
#define C2F (16.0f * 1.4426950408889634f)
#define W_WIN 8e-3f  // > 2*(fp16 sim err bound ~2e-3) + storage ulps: deterministic cover

typedef _Float16 half8 __attribute__((ext_vector_type(8)));
typedef __fp16 fp16x2 __attribute__((ext_vector_type(2)));
typedef float f32x4 __attribute__((ext_vector_type(4)));
union H8 { half8 v; fp16x2 h2[4]; };

// ws byte offsets (Nh aliases TV: TV dead after k_rescore, Nh written in k_gather)
#define OFF_PF 0u
#define OFF_PH 4194304u
#define OFF_TV 6291456u
#define OFF_NH 6291456u
#define OFF_RM 14680064u
#define OFF_KEY 14712832u
#define OFF_DG 14778368u
#define OFF_SP 14811136u
// total 15,073,280 bytes

__global__ __launch_bounds__(256) void k_normalize(const float* __restrict__ in1,
                                                   const float* __restrict__ in2,
                                                   float* __restrict__ Pf,
                                                   _Float16* __restrict__ Ph) {
  int t = threadIdx.x, w = t >> 6, l = t & 63;
  int g = blockIdx.x * 4 + w;  // 0..8191
  int view = g >> 12, row = g & (B_N - 1);
  const float* src = (view ? in2 : in1) + (size_t)row * D_N;
  float2 v = *(const float2*)(src + 2 * l);
  float ss = fmaf(v.x, v.x, v.y * v.y);
#pragma unroll
  for (int m = 1; m < 64; m <<= 1) ss += __shfl_xor(ss, m);
  float rn = 1.0f / sqrtf(ss);
  float2 o;
  o.x = v.x * rn;
  o.y = v.y * rn;
  *(float2*)(Pf + (size_t)g * D_N + 2 * l) = o;
  *(fp16x2*)(Ph + (size_t)g * D_N + 2 * l) = __builtin_amdgcn_cvt_pkrtz(o.x, o.y);
}

// ---- NN screen: per (p, 64-q-tile) approx max sim. No LDS, no barriers. ----
__global__ __launch_bounds__(256) void k_nn(const float* __restrict__ queue,
                                            const _Float16* __restrict__ Ph,
                                            _Float16* __restrict__ tv) {
  int bid = blockIdx.x;
  int chunk = bid & 7, pb = bid >> 3;  // chunk -> XCD for L2 locality
  int t = threadIdx.x, l = t & 63, w = t >> 6;
  int wq = w >> 1, wp = w & 1, l15 = l & 15, l4 = l >> 4;
  // stationary P fragments (B-operand): col = l&15, k = (l>>4)*8 + i
  half8 Pf4[4][4];
  const _Float16* pbase = Ph + (size_t)(pb * 128 + wp * 64 + l15) * D_N + l4 * 8;
#pragma unroll
  for (int tj = 0; tj < 4; ++tj)
#pragma unroll
    for (int ks = 0; ks < 4; ++ks)
      Pf4[tj][ks] = *(const half8*)(pbase + (size_t)tj * 16 * D_N + ks * 32);
  const float* qbase = queue + (size_t)(chunk * 4096 + wq * 64 + l15) * D_N + l4 * 8;
  int pcol = pb * 128 + wp * 64 + l15;
#pragma unroll 2
  for (int qt = 0; qt < 32; ++qt) {
    const float* qb = qbase + (size_t)qt * 128 * D_N;
    f32x4 acc[4][4];
#pragma unroll
    for (int i = 0; i < 4; ++i)
#pragma unroll
      for (int j = 0; j < 4; ++j) acc[i][j] = (f32x4){0.f, 0.f, 0.f, 0.f};
#pragma unroll
    for (int ks = 0; ks < 4; ++ks) {
      half8 Qf[4];
#pragma unroll
      for (int ti = 0; ti < 4; ++ti) {
        const float* a = qb + (size_t)ti * 16 * D_N + ks * 32;
        float4 x = *(const float4*)a;
        float4 y = *(const float4*)(a + 4);
        H8 h;
        h.h2[0] = __builtin_amdgcn_cvt_pkrtz(x.x, x.y);
        h.h2[1] = __builtin_amdgcn_cvt_pkrtz(x.z, x.w);
        h.h2[2] = __builtin_amdgcn_cvt_pkrtz(y.x, y.y);
        h.h2[3] = __builtin_amdgcn_cvt_pkrtz(y.z, y.w);
        Qf[ti] = h.v;
      }
#pragma unroll
      for (int ti = 0; ti < 4; ++ti)
#pragma unroll
        for (int tj = 0; tj < 4; ++tj)
          acc[ti][tj] =
              __builtin_amdgcn_mfma_f32_16x16x32_f16(Qf[ti], Pf4[tj][ks], acc[ti][tj], 0, 0, 0);
    }
    int tid = chunk * 64 + qt * 2 + wq;
#pragma unroll
    for (int tj = 0; tj < 4; ++tj) {
      float m = acc[0][tj][0];
#pragma unroll
      for (int ti = 0; ti < 4; ++ti)
#pragma unroll
        for (int r = 0; r < 4; ++r) m = fmaxf(m, acc[ti][tj][r]);
      m = fmaxf(m, __shfl_xor(m, 16));
      m = fmaxf(m, __shfl_xor(m, 32));
      if (l4 == 0) tv[(size_t)tid * NP + pcol + tj * 16] = (_Float16)m;
    }
  }
}

__global__ __launch_bounds__(256) void k_rowmax(const _Float16* __restrict__ tv,
                                                float* __restrict__ rowmax,
                                                unsigned long long* __restrict__ keys) {
  int p = blockIdx.x * 256 + threadIdx.x;
  float m = -3e38f;
  for (int tid = 0; tid < NTILE; ++tid) m = fmaxf(m, (float)tv[(size_t)tid * NP + p]);
  rowmax[p] = m;
  keys[p] = 0ull;  // any packed real value exceeds 0
}

// ---- exact fp32 rescore of candidate tiles; atomicMax(packed val,~idx) ----
__global__ __launch_bounds__(256) void k_rescore(const float* __restrict__ queue,
                                                 const float* __restrict__ Pf,
                                                 const _Float16* __restrict__ tv,
                                                 const float* __restrict__ rowmax,
                                                 unsigned long long* __restrict__ keys) {
  __shared__ float Qs[64][128];
  __shared__ int cand[1024];
  __shared__ int cnt;
  __shared__ float rv[64];
  __shared__ int ri[64];
  int tid = blockIdx.x, slab = blockIdx.y, t = threadIdx.x;
  if (t == 0) cnt = 0;
  __syncthreads();
  int pbase = slab * 1024;
#pragma unroll
  for (int j = 0; j < 4; ++j) {
    int p = pbase + j * 256 + t;
    float v = (float)tv[(size_t)tid * NP + p];
    if (v >= rowmax[p] - W_WIN) {
      int k = atomicAdd(&cnt, 1);
      cand[k] = p;
    }
  }
  __syncthreads();
  int n = cnt;
  if (n == 0) return;
  int qbase = (tid >> 6) * 4096 + ((tid >> 1) & 31) * 128 + (tid & 1) * 64;
#pragma unroll
  for (int j = 0; j < 8; ++j) {
    int i = j * 256 + t;
    int r = i >> 5, c = i & 31;
    *(float4*)(&Qs[r][c * 4]) = *(const float4*)(queue + (size_t)(qbase + r) * D_N + c * 4);
  }
  __syncthreads();
  int qr = t >> 2, quad = t & 3;
  for (int ci = 0; ci < n; ++ci) {
    int p = cand[ci];
    const float* pr = Pf + (size_t)p * D_N + quad * 32;
    float d = 0.f;
#pragma unroll
    for (int k = 0; k < 8; ++k) {
      float4 a = *(const float4*)(pr + k * 4);
      float4 b = *(const float4*)(&Qs[qr][quad * 32 + k * 4]);
      d = fmaf(a.x, b.x, d);
      d = fmaf(a.y, b.y, d);
      d = fmaf(a.z, b.z, d);
      d = fmaf(a.w, b.w, d);
    }
    d += __shfl_xor(d, 1);
    d += __shfl_xor(d, 2);
    if (quad == 0) {
      rv[qr] = d;
      ri[qr] = qbase + qr;
    }
    __syncthreads();
    if (t < 64) {
      float v = rv[t];
      int idx = ri[t];
#pragma unroll
      for (int m = 1; m < 64; m <<= 1) {
        float ov = __shfl_xor(v, m);
        int oi = __shfl_xor(idx, m);
        if (ov > v || (ov == v && oi < idx)) {
          v = ov;
          idx = oi;
        }
      }
      if (t == 0) {
        unsigned u = __float_as_uint(v);
        u = ((int)u < 0) ? ~u : (u | 0x80000000u);
        unsigned long long key = ((unsigned long long)u << 32) | (unsigned)(~idx);
        atomicMax(keys + p, key);
      }
    }
    __syncthreads();
  }
}

// ---- gather: n = p + (nn - p) fp32 (matches ref fp ops); fp16 copy; exact diag ----
__global__ __launch_bounds__(256) void k_gather(const float* __restrict__ queue,
                                                const float* __restrict__ Pf,
                                                const unsigned long long* __restrict__ keys,
                                                _Float16* __restrict__ Nh,
                                                float* __restrict__ diag) {
  int t = threadIdx.x, w = t >> 6, l = t & 63;
  int g = blockIdx.x * 4 + w;  // 0..8191
  int view = g >> 12, row = g & (B_N - 1);
  unsigned long long key = keys[g];
  int qidx = (int)(~(unsigned)(key & 0xffffffffull));
  const float* p = Pf + (size_t)g * D_N;
  const float* q = queue + (size_t)qidx * D_N;
  float2 pv = *(const float2*)(p + 2 * l);
  float2 qv = *(const float2*)(q + 2 * l);
  float2 nv;
  nv.x = pv.x + (qv.x - pv.x);
  nv.y = pv.y + (qv.y - pv.y);
  *(fp16x2*)(Nh + (size_t)g * D_N + 2 * l) = __builtin_amdgcn_cvt_pkrtz(nv.x, nv.y);
  const float* po = Pf + (size_t)((1 - view) * B_N + row) * D_N;
  float2 ov = *(const float2*)(po + 2 * l);
  float d = fmaf(nv.x, ov.x, nv.y * ov.y);
#pragma unroll
  for (int m = 1; m < 64; m <<= 1) d += __shfl_xor(d, m);
  if (l == 0) diag[g] = d;  // view0 -> pairs 0/1, view1 -> pairs 2/3
}

// ---- loss GEMM: fp16 MFMA + fixed-shift LSE partials over col chunks ----
__global__ __launch_bounds__(256) void k_loss(const _Float16* __restrict__ Ph,
                                              const _Float16* __restrict__ Nh,
                                              float* __restrict__ Spart) {
  __shared__ float sred[2][2][64];
  int rb = blockIdx.x;     // 0..127
  int chunk = blockIdx.y;  // 0..3
  int pair = rb >> 5, rowblk = rb & 31;
  const size_t BDh = (size_t)B_N * D_N;
  const _Float16* A = (pair == 0) ? Nh : (pair == 1) ? (Ph + BDh) : (pair == 2) ? (Nh + BDh) : Ph;
  const _Float16* Bm = (pair == 0) ? (Ph + BDh) : (pair == 1) ? Nh : (pair == 2) ? Ph : (Nh + BDh);
  int t = threadIdx.x, l = t & 63, w = t >> 6;
  int wr = w >> 1, wc = w & 1, l15 = l & 15, l4 = l >> 4;
  half8 Af[4][4];
  const _Float16* ab = A + (size_t)(rowblk * 128 + wr * 64 + l15) * D_N + l4 * 8;
#pragma unroll
  for (int ti = 0; ti < 4; ++ti)
#pragma unroll
    for (int ks = 0; ks < 4; ++ks) Af[ti][ks] = *(const half8*)(ab + (size_t)ti * 16 * D_N + ks * 32);
  float S[16];
#pragma unroll
  for (int i = 0; i < 16; ++i) S[i] = 0.f;
  const _Float16* bb = Bm + (size_t)(chunk * 1024 + wc * 64 + l15) * D_N + l4 * 8;
#pragma unroll 1
  for (int ct = 0; ct < 8; ++ct) {
    const _Float16* bt = bb + (size_t)ct * 128 * D_N;
    f32x4 acc[4][4];
#pragma unroll
    for (int i = 0; i < 4; ++i)
#pragma unroll
      for (int j = 0; j < 4; ++j) acc[i][j] = (f32x4){0.f, 0.f, 0.f, 0.f};
#pragma unroll
    for (int ks = 0; ks < 4; ++ks) {
      half8 Bf[4];
#pragma unroll
      for (int tj = 0; tj < 4; ++tj) Bf[tj] = *(const half8*)(bt + (size_t)tj * 16 * D_N + ks * 32);
#pragma unroll
      for (int ti = 0; ti < 4; ++ti)
#pragma unroll
        for (int tj = 0; tj < 4; ++tj)
          acc[ti][tj] = __builtin_amdgcn_mfma_f32_16x16x32_f16(Af[ti][ks], Bf[tj], acc[ti][tj], 0, 0, 0);
    }
#pragma unroll
    for (int ti = 0; ti < 4; ++ti)
#pragma unroll
      for (int r = 0; r < 4; ++r) {
        float e = 0.f;
#pragma unroll
        for (int tj = 0; tj < 4; ++tj) e += exp2f(fmaf(acc[ti][tj][r], C1F, -C2F));
        S[ti * 4 + r] += e;
      }
  }
#pragma unroll
  for (int i = 0; i < 16; ++i) {
#pragma unroll
    for (int m = 1; m < 16; m <<= 1) S[i] += __shfl_xor(S[i], m);
  }
  if (l15 == 0) {
#pragma unroll
    for (int ti = 0; ti < 4; ++ti)
#pragma unroll
      for (int r = 0; r < 4; ++r) sred[wr][wc][ti * 16 + l4 * 4 + r] = S[ti * 4 + r];
  }
  __syncthreads();
  if (t < 128) {
    int wrr = t >> 6, rl = t & 63;
    float s = sred[wrr][0][rl] + sred[wrr][1][rl];
    int row = pair * B_N + rowblk * 128 + wrr * 64 + rl;
    Spart[(size_t)row * 4 + chunk] = s;
  }
}

__global__ __launch_bounds__(256) void k_merge(const float* __restrict__ Spart,
                                               const float* __restrict__ diag,
                                               float* __restrict__ out) {
  int row = blockIdx.x * 256 + threadIdx.x;  // 0..16383
  const float* sp = Spart + (size_t)row * 4;
  float s = sp[0] + sp[1] + sp[2] + sp[3];
  int pair = row >> 12, r = row & (B_N - 1);
  float dg = diag[(pair >> 1) * B_N + r];
  out[row] = logf(s) + 16.0f - INV_T * dg;
}

extern "C" void kernel_launch(void* const* d_in, const int* in_sizes, int n_in,
                              void* d_out, int out_size, void* d_ws, size_t ws_size,
                              hipStream_t stream) {
  const float* in1 = (const float*)d_in[0];
  const float* in2 = (const float*)d_in[1];
  const float* queue = (const float*)d_in[2];
  float* out = (float*)d_out;
  char* ws = (char*)d_ws;
  float* Pf = (float*)(ws + OFF_PF);
  _Float16* Ph = (_Float16*)(ws + OFF_PH);
  _Float16* TV = (_Float16*)(ws + OFF_TV);
  _Float16* Nh = (_Float16*)(ws + OFF_NH);
  float* RM = (float*)(ws + OFF_RM);
  unsigned long long* KEY = (unsigned long long*)(ws + OFF_KEY);
  float* DG = (float*)(ws + OFF_DG);
  float* SP = (float*)(ws + OFF_SP);

  hipLaunchKernelGGL(k_normalize, dim3(2048), dim3(256), 0, stream, in1, in2, Pf, Ph);
  hipLaunchKernelGGL(k_nn, dim3(512), dim3(256), 0, stream, queue, Ph, TV);
  hipLaunchKernelGGL(k_rowmax, dim3(32), dim3(256), 0, stream, TV, RM, KEY);
  hipLaunchKernelGGL(k_rescore, dim3(512, 8), dim3(256), 0, stream, queue, Pf, TV, RM, KEY);
  hipLaunchKernelGGL(k_gather, dim3(2048), dim3(256), 0, stream, queue, Pf, KEY, Nh, DG);
  hipLaunchKernelGGL(k_loss, dim3(128, 4), dim3(256), 0, stream, Ph, Nh, SP);
  hipLaunchKernelGGL(k_merge, dim3(64), dim3(256), 0, stream, SP, DG, out);
}

// Round 4
// 208.103 us; speedup vs baseline: 5.1921x; 2.1039x over previous
//
#include <hip/hip_runtime.h>
#include <math.h>

// NNCLR forward loss. fp16 MFMA GEMMs with LDS-staged tiles (global_load_lds +
// XOR swizzle), deterministic fp32 rescore for argmax (scale-invariant: uses raw
// input rows), fixed-shift LSE for the loss.
// normalize -> [qcvt(h) -> k_nn(h)]x2 -> rowmax1/2 -> rescore -> gather -> loss -> merge

#define B_N 4096
#define D_N 128
#define NP 8192    // 2*B p-rows
#define NTILE 512  // 64-wide q tiles
#define INV_T 10.0f
#define C1F (10.0f * 1.4426950408889634f)
#define C2F (16.0f * 1.4426950408889634f)
#define W_WIN 8e-3f  // > 2*(fp16 sim err ~2.5e-3): deterministic candidate cover

typedef _Float16 half8 __attribute__((ext_vector_type(8)));
typedef __fp16 fp16x2 __attribute__((ext_vector_type(2)));
typedef float f32x4 __attribute__((ext_vector_type(4)));
union H8 { half8 v; fp16x2 h2[4]; };

// ws byte offsets (total 15,039,488 <= proven 15,073,280)
#define OFF_PH 0u        // 2 MB  normalized p fp16 [8192][128]
#define OFF_QH 2097152u  // 4 MB  fp16 queue half [16384][128]; NH aliases after k_nn
#define OFF_NH 2097152u  // 2 MB  fp16 neighbours [8192][128]
#define OFF_TV 6291456u  // 8 MB  [512][8192] fp16 tile maxes; DG/SP alias after rescore
#define OFF_DG 6291456u  // 32 KB
#define OFF_SP 6324224u  // 256 KB
#define OFF_RM1 14680064u  // 256 KB [8][8192] f32 partial rowmax
#define OFF_RM 14942208u   // 32 KB
#define OFF_KEY 14974976u  // 64 KB

__device__ __forceinline__ void gload16(const void* g, void* l) {
  __builtin_amdgcn_global_load_lds((const __attribute__((address_space(1))) void*)g,
                                   (__attribute__((address_space(3))) void*)l, 16, 0, 0);
}

__global__ __launch_bounds__(256) void k_normalize(const float* __restrict__ in1,
                                                   const float* __restrict__ in2,
                                                   _Float16* __restrict__ Ph) {
  int t = threadIdx.x, w = t >> 6, l = t & 63;
  int g = blockIdx.x * 4 + w;  // 0..8191
  int view = g >> 12, row = g & (B_N - 1);
  const float* src = (view ? in2 : in1) + (size_t)row * D_N;
  float2 v = *(const float2*)(src + 2 * l);
  float ss = fmaf(v.x, v.x, v.y * v.y);
#pragma unroll
  for (int m = 1; m < 64; m <<= 1) ss += __shfl_xor(ss, m);
  float rn = 1.0f / sqrtf(ss);
  *(fp16x2*)(Ph + (size_t)g * D_N + 2 * l) = __builtin_amdgcn_cvt_pkrtz(v.x * rn, v.y * rn);
}

__global__ __launch_bounds__(256) void k_qcvt(const float* __restrict__ src,
                                              _Float16* __restrict__ dst) {
  int i = blockIdx.x * 256 + threadIdx.x;  // half8 groups; grid 1024 covers 16384 rows
  const float* s = src + (size_t)i * 8;
  float4 x = *(const float4*)s;
  float4 y = *(const float4*)(s + 4);
  H8 h;
  h.h2[0] = __builtin_amdgcn_cvt_pkrtz(x.x, x.y);
  h.h2[1] = __builtin_amdgcn_cvt_pkrtz(x.z, x.w);
  h.h2[2] = __builtin_amdgcn_cvt_pkrtz(y.x, y.y);
  h.h2[3] = __builtin_amdgcn_cvt_pkrtz(y.z, y.w);
  *(half8*)(dst + (size_t)i * 8) = h.v;
}

// ---- NN screen: 128p x 2048q per block; Q staged in LDS (dbuf + swizzle) ----
__global__ __launch_bounds__(256, 2) void k_nn(const _Float16* __restrict__ Qh,
                                               const _Float16* __restrict__ Ph,
                                               _Float16* __restrict__ tv, int h) {
  __shared__ _Float16 sm[2][16384];  // 2 x 32 KB (128 rows x 128 d fp16)
  int bid = blockIdx.x;
  int c2 = bid & 7, pb = bid >> 3;  // c2 -> XCD: 2048-q chunk L2-resident
  int t = threadIdx.x, l = t & 63, w = t >> 6;
  int wq = w >> 1, wp = w & 1, l15 = l & 15, l4 = l >> 4;
  // stationary P fragments (B-operand)
  half8 Pf4[4][4];
  const _Float16* pbase = Ph + (size_t)(pb * 128 + wp * 64 + l15) * D_N + l4 * 8;
#pragma unroll
  for (int tj = 0; tj < 4; ++tj)
#pragma unroll
    for (int ks = 0; ks < 4; ++ks)
      Pf4[tj][ks] = *(const half8*)(pbase + (size_t)tj * 16 * D_N + ks * 32);
  int tidb = h * 256 + c2 * 32;
  int pcol = pb * 128 + wp * 64 + l15;
  // prologue stage qt=0
  {
    int qrow0 = c2 * 2048;
#pragma unroll
    for (int j = 0; j < 8; ++j) {
      int r = ((w * 8 + j) << 2) + l4;
      const _Float16* src = Qh + ((size_t)(qrow0 + r) << 7) + ((l15 ^ (r & 7)) << 3);
      gload16(src, (char*)(&sm[0][0]) + ((w * 8 + j) << 10));
    }
  }
#pragma unroll 1
  for (int qt = 0; qt < 16; ++qt) {
    int cur = qt & 1;
    __syncthreads();
    if (qt + 1 < 16) {
      int qrow0 = c2 * 2048 + (qt + 1) * 128;
#pragma unroll
      for (int j = 0; j < 8; ++j) {
        int r = ((w * 8 + j) << 2) + l4;
        const _Float16* src = Qh + ((size_t)(qrow0 + r) << 7) + ((l15 ^ (r & 7)) << 3);
        gload16(src, (char*)(&sm[cur ^ 1][0]) + ((w * 8 + j) << 10));
      }
    }
    const char* bb = (const char*)(&sm[cur][0]);
    f32x4 acc[4][4];
#pragma unroll
    for (int i = 0; i < 4; ++i)
#pragma unroll
      for (int j = 0; j < 4; ++j) acc[i][j] = (f32x4){0.f, 0.f, 0.f, 0.f};
#pragma unroll
    for (int ks = 0; ks < 4; ++ks) {
      half8 Qf[4];
#pragma unroll
      for (int ti = 0; ti < 4; ++ti) {
        int qloc = wq * 64 + ti * 16 + l15;
        int byteo = qloc * 256 + ((((ks << 2) + l4) ^ (qloc & 7)) << 4);
        Qf[ti] = *(const half8*)(bb + byteo);
      }
#pragma unroll
      for (int ti = 0; ti < 4; ++ti)
#pragma unroll
        for (int tj = 0; tj < 4; ++tj)
          acc[ti][tj] =
              __builtin_amdgcn_mfma_f32_16x16x32_f16(Qf[ti], Pf4[tj][ks], acc[ti][tj], 0, 0, 0);
    }
    int tid = tidb + qt * 2 + wq;
#pragma unroll
    for (int tj = 0; tj < 4; ++tj) {
      float m = acc[0][tj][0];
#pragma unroll
      for (int ti = 0; ti < 4; ++ti)
#pragma unroll
        for (int r = 0; r < 4; ++r) m = fmaxf(m, acc[ti][tj][r]);
      m = fmaxf(m, __shfl_xor(m, 16));
      m = fmaxf(m, __shfl_xor(m, 32));
      if (l4 == 0) tv[(size_t)tid * NP + pcol + tj * 16] = (_Float16)m;
    }
  }
}

__global__ __launch_bounds__(256) void k_rowmax1(const _Float16* __restrict__ tv,
                                                 float* __restrict__ rm1) {
  int p = blockIdx.x * 256 + threadIdx.x;
  int g = blockIdx.y;
  float m = -3e38f;
  for (int tid = g * 64; tid < g * 64 + 64; ++tid) m = fmaxf(m, (float)tv[(size_t)tid * NP + p]);
  rm1[(size_t)g * NP + p] = m;
}

__global__ __launch_bounds__(256) void k_rowmax2(const float* __restrict__ rm1,
                                                 float* __restrict__ rowmax,
                                                 unsigned long long* __restrict__ keys) {
  int p = blockIdx.x * 256 + threadIdx.x;
  float m = rm1[p];
#pragma unroll
  for (int g = 1; g < 8; ++g) m = fmaxf(m, rm1[(size_t)g * NP + p]);
  rowmax[p] = m;
  keys[p] = 0ull;
}

// ---- exact fp32 rescore on RAW input rows (argmax scale-invariant) ----
__global__ __launch_bounds__(256) void k_rescore(const float* __restrict__ queue,
                                                 const float* __restrict__ in1,
                                                 const float* __restrict__ in2,
                                                 const _Float16* __restrict__ tv,
                                                 const float* __restrict__ rowmax,
                                                 unsigned long long* __restrict__ keys) {
  __shared__ float Qs[64][128];
  __shared__ int cand[1024];
  __shared__ int cnt;
  __shared__ float rv[64];
  __shared__ int ri[64];
  int tid = blockIdx.x, slab = blockIdx.y, t = threadIdx.x;
  if (t == 0) cnt = 0;
  __syncthreads();
  int pbase = slab * 1024;
#pragma unroll
  for (int j = 0; j < 4; ++j) {
    int p = pbase + j * 256 + t;
    float v = (float)tv[(size_t)tid * NP + p];
    if (v >= rowmax[p] - W_WIN) {
      int k = atomicAdd(&cnt, 1);
      cand[k] = p;
    }
  }
  __syncthreads();
  int n = cnt;
  if (n == 0) return;
  int qbase = tid << 6;
#pragma unroll
  for (int j = 0; j < 8; ++j) {
    int i = j * 256 + t;
    int r = i >> 5, c = i & 31;
    *(float4*)(&Qs[r][c * 4]) = *(const float4*)(queue + (size_t)(qbase + r) * D_N + c * 4);
  }
  __syncthreads();
  int qr = t >> 2, quad = t & 3;
  for (int ci = 0; ci < n; ++ci) {
    int p = cand[ci];
    const float* prow = (p < B_N) ? (in1 + (size_t)p * D_N) : (in2 + (size_t)(p - B_N) * D_N);
    const float* pr = prow + quad * 32;
    float d = 0.f;
#pragma unroll
    for (int k = 0; k < 8; ++k) {
      float4 a = *(const float4*)(pr + k * 4);
      float4 b = *(const float4*)(&Qs[qr][quad * 32 + k * 4]);
      d = fmaf(a.x, b.x, d);
      d = fmaf(a.y, b.y, d);
      d = fmaf(a.z, b.z, d);
      d = fmaf(a.w, b.w, d);
    }
    d += __shfl_xor(d, 1);
    d += __shfl_xor(d, 2);
    if (quad == 0) {
      rv[qr] = d;
      ri[qr] = qbase + qr;
    }
    __syncthreads();
    if (t < 64) {
      float v = rv[t];
      int idx = ri[t];
#pragma unroll
      for (int m = 1; m < 64; m <<= 1) {
        float ov = __shfl_xor(v, m);
        int oi = __shfl_xor(idx, m);
        if (ov > v || (ov == v && oi < idx)) {
          v = ov;
          idx = oi;
        }
      }
      if (t == 0) {
        unsigned u = __float_as_uint(v);
        u = ((int)u < 0) ? ~u : (u | 0x80000000u);
        unsigned long long key = ((unsigned long long)u << 32) | (unsigned)(~idx);
        atomicMax(keys + p, key);
      }
    }
    __syncthreads();
  }
}

// ---- gather: Nh = fp16(queue[idx]); diag = dot(nn, p_other) exact fp32 ----
__global__ __launch_bounds__(256) void k_gather(const float* __restrict__ queue,
                                                const float* __restrict__ in1,
                                                const float* __restrict__ in2,
                                                const unsigned long long* __restrict__ keys,
                                                _Float16* __restrict__ Nh,
                                                float* __restrict__ diag) {
  int t = threadIdx.x, w = t >> 6, l = t & 63;
  int g = blockIdx.x * 4 + w;  // 0..8191
  int view = g >> 12, row = g & (B_N - 1);
  unsigned long long key = keys[g];
  int qidx = (int)(~(unsigned)(key & 0xffffffffull));
  const float* q = queue + (size_t)qidx * D_N;
  float2 qv = *(const float2*)(q + 2 * l);
  *(fp16x2*)(Nh + (size_t)g * D_N + 2 * l) = __builtin_amdgcn_cvt_pkrtz(qv.x, qv.y);
  const float* oth = (view ? in1 : in2) + (size_t)row * D_N;
  float2 ov = *(const float2*)(oth + 2 * l);
  float ss = fmaf(ov.x, ov.x, ov.y * ov.y);
  float d = fmaf(qv.x, ov.x, qv.y * ov.y);
#pragma unroll
  for (int m = 1; m < 64; m <<= 1) {
    ss += __shfl_xor(ss, m);
    d += __shfl_xor(d, m);
  }
  if (l == 0) diag[g] = d / sqrtf(ss);
}

// ---- loss GEMM: LDS-staged B tiles + stationary A frags + fixed-shift LSE ----
__global__ __launch_bounds__(256, 2) void k_loss(const _Float16* __restrict__ Ph,
                                                 const _Float16* __restrict__ Nh,
                                                 float* __restrict__ Spart) {
  __shared__ _Float16 sm[2][16384];
  __shared__ float sred[2][2][64];
  int rb = blockIdx.x;     // 0..127
  int chunk = blockIdx.y;  // 0..3
  int pair = rb >> 5, rowblk = rb & 31;
  const size_t BDh = (size_t)B_N * D_N;
  const _Float16* A = (pair == 0) ? Nh : (pair == 1) ? (Ph + BDh) : (pair == 2) ? (Nh + BDh) : Ph;
  const _Float16* Bm = (pair == 0) ? (Ph + BDh) : (pair == 1) ? Nh : (pair == 2) ? Ph : (Nh + BDh);
  int t = threadIdx.x, l = t & 63, w = t >> 6;
  int wr = w >> 1, wc = w & 1, l15 = l & 15, l4 = l >> 4;
  half8 Af[4][4];
  const _Float16* ab = A + (size_t)(rowblk * 128 + wr * 64 + l15) * D_N + l4 * 8;
#pragma unroll
  for (int ti = 0; ti < 4; ++ti)
#pragma unroll
    for (int ks = 0; ks < 4; ++ks)
      Af[ti][ks] = *(const half8*)(ab + (size_t)ti * 16 * D_N + ks * 32);
  float S[16];
#pragma unroll
  for (int i = 0; i < 16; ++i) S[i] = 0.f;
  // prologue stage ct=0
  {
    int crow0 = chunk * 1024;
#pragma unroll
    for (int j = 0; j < 8; ++j) {
      int r = ((w * 8 + j) << 2) + l4;
      const _Float16* src = Bm + ((size_t)(crow0 + r) << 7) + ((l15 ^ (r & 7)) << 3);
      gload16(src, (char*)(&sm[0][0]) + ((w * 8 + j) << 10));
    }
  }
#pragma unroll 1
  for (int ct = 0; ct < 8; ++ct) {
    int cur = ct & 1;
    __syncthreads();
    if (ct + 1 < 8) {
      int crow0 = chunk * 1024 + (ct + 1) * 128;
#pragma unroll
      for (int j = 0; j < 8; ++j) {
        int r = ((w * 8 + j) << 2) + l4;
        const _Float16* src = Bm + ((size_t)(crow0 + r) << 7) + ((l15 ^ (r & 7)) << 3);
        gload16(src, (char*)(&sm[cur ^ 1][0]) + ((w * 8 + j) << 10));
      }
    }
    const char* bbp = (const char*)(&sm[cur][0]);
    f32x4 acc[4][4];
#pragma unroll
    for (int i = 0; i < 4; ++i)
#pragma unroll
      for (int j = 0; j < 4; ++j) acc[i][j] = (f32x4){0.f, 0.f, 0.f, 0.f};
#pragma unroll
    for (int ks = 0; ks < 4; ++ks) {
      half8 Bf[4];
#pragma unroll
      for (int tj = 0; tj < 4; ++tj) {
        int bloc = wc * 64 + tj * 16 + l15;
        int byteo = bloc * 256 + ((((ks << 2) + l4) ^ (bloc & 7)) << 4);
        Bf[tj] = *(const half8*)(bbp + byteo);
      }
#pragma unroll
      for (int ti = 0; ti < 4; ++ti)
#pragma unroll
        for (int tj = 0; tj < 4; ++tj)
          acc[ti][tj] =
              __builtin_amdgcn_mfma_f32_16x16x32_f16(Af[ti][ks], Bf[tj], acc[ti][tj], 0, 0, 0);
    }
#pragma unroll
    for (int ti = 0; ti < 4; ++ti)
#pragma unroll
      for (int r = 0; r < 4; ++r) {
        float e = 0.f;
#pragma unroll
        for (int tj = 0; tj < 4; ++tj) e += exp2f(fmaf(acc[ti][tj][r], C1F, -C2F));
        S[ti * 4 + r] += e;
      }
  }
#pragma unroll
  for (int i = 0; i < 16; ++i) {
#pragma unroll
    for (int m = 1; m < 16; m <<= 1) S[i] += __shfl_xor(S[i], m);
  }
  __syncthreads();
  if (l15 == 0) {
#pragma unroll
    for (int ti = 0; ti < 4; ++ti)
#pragma unroll
      for (int r = 0; r < 4; ++r) sred[wr][wc][ti * 16 + l4 * 4 + r] = S[ti * 4 + r];
  }
  __syncthreads();
  if (t < 128) {
    int wrr = t >> 6, rl = t & 63;
    float s = sred[wrr][0][rl] + sred[wrr][1][rl];
    int row = pair * B_N + rowblk * 128 + wrr * 64 + rl;
    Spart[(size_t)row * 4 + chunk] = s;
  }
}

__global__ __launch_bounds__(256) void k_merge(const float* __restrict__ Spart,
                                               const float* __restrict__ diag,
                                               float* __restrict__ out) {
  int row = blockIdx.x * 256 + threadIdx.x;  // 0..16383
  const float* sp = Spart + (size_t)row * 4;
  float s = sp[0] + sp[1] + sp[2] + sp[3];
  int pair = row >> 12, r = row & (B_N - 1);
  float dg = diag[(pair >> 1) * B_N + r];
  out[row] = logf(s) + 16.0f - INV_T * dg;
}

extern "C" void kernel_launch(void* const* d_in, const int* in_sizes, int n_in,
                              void* d_out, int out_size, void* d_ws, size_t ws_size,
                              hipStream_t stream) {
  const float* in1 = (const float*)d_in[0];
  const float* in2 = (const float*)d_in[1];
  const float* queue = (const float*)d_in[2];
  float* out = (float*)d_out;
  char* ws = (char*)d_ws;
  _Float16* Ph = (_Float16*)(ws + OFF_PH);
  _Float16* Qhh = (_Float16*)(ws + OFF_QH);
  _Float16* Nh = (_Float16*)(ws + OFF_NH);
  _Float16* TV = (_Float16*)(ws + OFF_TV);
  float* DG = (float*)(ws + OFF_DG);
  float* SP = (float*)(ws + OFF_SP);
  float* RM1 = (float*)(ws + OFF_RM1);
  float* RM = (float*)(ws + OFF_RM);
  unsigned long long* KEY = (unsigned long long*)(ws + OFF_KEY);

  hipLaunchKernelGGL(k_normalize, dim3(2048), dim3(256), 0, stream, in1, in2, Ph);
  for (int h = 0; h < 2; ++h) {
    hipLaunchKernelGGL(k_qcvt, dim3(1024), dim3(256), 0, stream, queue + (size_t)h * 16384 * D_N,
                       Qhh);
    hipLaunchKernelGGL(k_nn, dim3(512), dim3(256), 0, stream, Qhh, Ph, TV, h);
  }
  hipLaunchKernelGGL(k_rowmax1, dim3(32, 8), dim3(256), 0, stream, TV, RM1);
  hipLaunchKernelGGL(k_rowmax2, dim3(32), dim3(256), 0, stream, RM1, RM, KEY);
  hipLaunchKernelGGL(k_rescore, dim3(512, 8), dim3(256), 0, stream, queue, in1, in2, TV, RM, KEY);
  hipLaunchKernelGGL(k_gather, dim3(2048), dim3(256), 0, stream, queue, in1, in2, KEY, Nh, DG);
  hipLaunchKernelGGL(k_loss, dim3(128, 4), dim3(256), 0, stream, Ph, Nh, SP);
  hipLaunchKernelGGL(k_merge, dim3(64), dim3(256), 0, stream, SP, DG, out);
}

// Round 5
// 180.135 us; speedup vs baseline: 5.9982x; 1.1553x over previous
//
#include <hip/hip_runtime.h>
#include <math.h>

// NNCLR forward loss. fp16 MFMA GEMMs with LDS-staged tiles (global_load_lds +
// XOR swizzle), deterministic fp32 rescore for argmax (scale-invariant: uses raw
// input rows), fixed-shift LSE for the loss.
// normalize -> [qcvt(h) -> k_nn(h)]x2 -> rowmax1/2 -> rescore(per-tile) -> gather -> loss -> merge

#define B_N 4096
#define D_N 128
#define NP 8192    // 2*B p-rows
#define NTILE 512  // 64-wide q tiles
#define INV_T 10.0f
#define C1F (10.0f * 1.4426950408889634f)
#define C2F (16.0f * 1.4426950408889634f)
#define W_WIN 8e-3f  // > 2*(fp16 sim err ~2.5e-3): deterministic candidate cover

typedef _Float16 half8 __attribute__((ext_vector_type(8)));
typedef __fp16 fp16x2 __attribute__((ext_vector_type(2)));
typedef float f32x4 __attribute__((ext_vector_type(4)));
union H8 { half8 v; fp16x2 h2[4]; };

// ws byte offsets (total 15,039,488 <= proven 15,073,280)
#define OFF_PH 0u        // 2 MB  normalized p fp16 [8192][128]
#define OFF_QH 2097152u  // 4 MB  fp16 queue half [16384][128]; NH aliases after k_nn
#define OFF_NH 2097152u  // 2 MB  fp16 neighbours [8192][128]
#define OFF_TV 6291456u  // 8 MB  [512][8192] fp16 tile maxes; DG/SP alias after rescore
#define OFF_DG 6291456u  // 32 KB
#define OFF_SP 6324224u  // 256 KB
#define OFF_RM1 14680064u  // 256 KB [8][8192] f32 partial rowmax
#define OFF_RM 14942208u   // 32 KB
#define OFF_KEY 14974976u  // 64 KB

__device__ __forceinline__ void gload16(const void* g, void* l) {
  __builtin_amdgcn_global_load_lds((const __attribute__((address_space(1))) void*)g,
                                   (__attribute__((address_space(3))) void*)l, 16, 0, 0);
}

__global__ __launch_bounds__(256) void k_normalize(const float* __restrict__ in1,
                                                   const float* __restrict__ in2,
                                                   _Float16* __restrict__ Ph) {
  int t = threadIdx.x, w = t >> 6, l = t & 63;
  int g = blockIdx.x * 4 + w;  // 0..8191
  int view = g >> 12, row = g & (B_N - 1);
  const float* src = (view ? in2 : in1) + (size_t)row * D_N;
  float2 v = *(const float2*)(src + 2 * l);
  float ss = fmaf(v.x, v.x, v.y * v.y);
#pragma unroll
  for (int m = 1; m < 64; m <<= 1) ss += __shfl_xor(ss, m);
  float rn = 1.0f / sqrtf(ss);
  *(fp16x2*)(Ph + (size_t)g * D_N + 2 * l) = __builtin_amdgcn_cvt_pkrtz(v.x * rn, v.y * rn);
}

__global__ __launch_bounds__(256) void k_qcvt(const float* __restrict__ src,
                                              _Float16* __restrict__ dst) {
  int i = blockIdx.x * 256 + threadIdx.x;  // half8 groups; grid 1024 covers 16384 rows
  const float* s = src + (size_t)i * 8;
  float4 x = *(const float4*)s;
  float4 y = *(const float4*)(s + 4);
  H8 h;
  h.h2[0] = __builtin_amdgcn_cvt_pkrtz(x.x, x.y);
  h.h2[1] = __builtin_amdgcn_cvt_pkrtz(x.z, x.w);
  h.h2[2] = __builtin_amdgcn_cvt_pkrtz(y.x, y.y);
  h.h2[3] = __builtin_amdgcn_cvt_pkrtz(y.z, y.w);
  *(half8*)(dst + (size_t)i * 8) = h.v;
}

// ---- NN screen: 128p x 2048q per block; Q staged in LDS (dbuf + swizzle) ----
__global__ __launch_bounds__(256, 2) void k_nn(const _Float16* __restrict__ Qh,
                                               const _Float16* __restrict__ Ph,
                                               _Float16* __restrict__ tv, int h) {
  __shared__ _Float16 sm[2][16384];  // 2 x 32 KB (128 rows x 128 d fp16)
  int bid = blockIdx.x;
  int c2 = bid & 7, pb = bid >> 3;  // c2 -> XCD: 2048-q chunk L2-resident
  int t = threadIdx.x, l = t & 63, w = t >> 6;
  int wq = w >> 1, wp = w & 1, l15 = l & 15, l4 = l >> 4;
  // stationary P fragments (B-operand)
  half8 Pf4[4][4];
  const _Float16* pbase = Ph + (size_t)(pb * 128 + wp * 64 + l15) * D_N + l4 * 8;
#pragma unroll
  for (int tj = 0; tj < 4; ++tj)
#pragma unroll
    for (int ks = 0; ks < 4; ++ks)
      Pf4[tj][ks] = *(const half8*)(pbase + (size_t)tj * 16 * D_N + ks * 32);
  int tidb = h * 256 + c2 * 32;
  int pcol = pb * 128 + wp * 64 + l15;
  // prologue stage qt=0
  {
    int qrow0 = c2 * 2048;
#pragma unroll
    for (int j = 0; j < 8; ++j) {
      int r = ((w * 8 + j) << 2) + l4;
      const _Float16* src = Qh + ((size_t)(qrow0 + r) << 7) + ((l15 ^ (r & 7)) << 3);
      gload16(src, (char*)(&sm[0][0]) + ((w * 8 + j) << 10));
    }
  }
#pragma unroll 1
  for (int qt = 0; qt < 16; ++qt) {
    int cur = qt & 1;
    __syncthreads();
    if (qt + 1 < 16) {
      int qrow0 = c2 * 2048 + (qt + 1) * 128;
#pragma unroll
      for (int j = 0; j < 8; ++j) {
        int r = ((w * 8 + j) << 2) + l4;
        const _Float16* src = Qh + ((size_t)(qrow0 + r) << 7) + ((l15 ^ (r & 7)) << 3);
        gload16(src, (char*)(&sm[cur ^ 1][0]) + ((w * 8 + j) << 10));
      }
    }
    const char* bb = (const char*)(&sm[cur][0]);
    f32x4 acc[4][4];
#pragma unroll
    for (int i = 0; i < 4; ++i)
#pragma unroll
      for (int j = 0; j < 4; ++j) acc[i][j] = (f32x4){0.f, 0.f, 0.f, 0.f};
#pragma unroll
    for (int ks = 0; ks < 4; ++ks) {
      half8 Qf[4];
#pragma unroll
      for (int ti = 0; ti < 4; ++ti) {
        int qloc = wq * 64 + ti * 16 + l15;
        int byteo = qloc * 256 + ((((ks << 2) + l4) ^ (qloc & 7)) << 4);
        Qf[ti] = *(const half8*)(bb + byteo);
      }
#pragma unroll
      for (int ti = 0; ti < 4; ++ti)
#pragma unroll
        for (int tj = 0; tj < 4; ++tj)
          acc[ti][tj] =
              __builtin_amdgcn_mfma_f32_16x16x32_f16(Qf[ti], Pf4[tj][ks], acc[ti][tj], 0, 0, 0);
    }
    int tid = tidb + qt * 2 + wq;
#pragma unroll
    for (int tj = 0; tj < 4; ++tj) {
      float m = acc[0][tj][0];
#pragma unroll
      for (int ti = 0; ti < 4; ++ti)
#pragma unroll
        for (int r = 0; r < 4; ++r) m = fmaxf(m, acc[ti][tj][r]);
      m = fmaxf(m, __shfl_xor(m, 16));
      m = fmaxf(m, __shfl_xor(m, 32));
      if (l4 == 0) tv[(size_t)tid * NP + pcol + tj * 16] = (_Float16)m;
    }
  }
}

__global__ __launch_bounds__(256) void k_rowmax1(const _Float16* __restrict__ tv,
                                                 float* __restrict__ rm1) {
  int p = blockIdx.x * 256 + threadIdx.x;
  int g = blockIdx.y;
  float m = -3e38f;
  for (int tid = g * 64; tid < g * 64 + 64; ++tid) m = fmaxf(m, (float)tv[(size_t)tid * NP + p]);
  rm1[(size_t)g * NP + p] = m;
}

__global__ __launch_bounds__(256) void k_rowmax2(const float* __restrict__ rm1,
                                                 float* __restrict__ rowmax,
                                                 unsigned long long* __restrict__ keys) {
  int p = blockIdx.x * 256 + threadIdx.x;
  float m = rm1[p];
#pragma unroll
  for (int g = 1; g < 8; ++g) m = fmaxf(m, rm1[(size_t)g * NP + p]);
  rowmax[p] = m;
  keys[p] = 0ull;
}

// ---- exact fp32 rescore, ONE BLOCK PER TILE: scan column -> cand list ->
//      Q tile in LDS once -> 4 candidates in flight (one per wave) ----
__global__ __launch_bounds__(256) void k_rescore(const float* __restrict__ queue,
                                                 const float* __restrict__ in1,
                                                 const float* __restrict__ in2,
                                                 const _Float16* __restrict__ tv,
                                                 const float* __restrict__ rowmax,
                                                 unsigned long long* __restrict__ keys) {
  __shared__ float Qs[64][132];  // pad 132: lane-per-row b128 reads spread all 8 bank-groups
  __shared__ unsigned short cand[NP];  // provably sufficient cap
  __shared__ int cnt;
  int tile = blockIdx.x;  // 0..511
  int t = threadIdx.x;
  if (t == 0) cnt = 0;
  __syncthreads();
  // stage Q tile (64 x 128 f32) once
  int qbase = tile << 6;
#pragma unroll
  for (int j = 0; j < 8; ++j) {
    int i = j * 256 + t;  // 0..2047 float4s
    int r = i >> 5, c = i & 31;
    *(float4*)(&Qs[r][c << 2]) = *(const float4*)(queue + ((size_t)(qbase + r) << 7) + (c << 2));
  }
  // scan this tile's TV column, build candidate list
  const _Float16* tvrow = tv + (size_t)tile * NP;
#pragma unroll
  for (int j = 0; j < 32; ++j) {
    int p = j * 256 + t;
    float v = (float)tvrow[p];
    if (v >= rowmax[p] - W_WIN) {
      int k = atomicAdd(&cnt, 1);
      cand[k] = (unsigned short)p;
    }
  }
  __syncthreads();
  int n = cnt;
  int w = t >> 6, l = t & 63;
  for (int ci = w; ci < n; ci += 4) {
    int p = cand[ci];
    const float* prow = (p < B_N) ? (in1 + ((size_t)p << 7)) : (in2 + ((size_t)(p - B_N) << 7));
    float d = 0.f;
#pragma unroll
    for (int k = 0; k < 32; ++k) {
      float4 a = *(const float4*)(prow + (k << 2));
      float4 b = *(const float4*)(&Qs[l][k << 2]);
      d = fmaf(a.x, b.x, d);
      d = fmaf(a.y, b.y, d);
      d = fmaf(a.z, b.z, d);
      d = fmaf(a.w, b.w, d);
    }
    int idx = qbase + l;
#pragma unroll
    for (int m = 1; m < 64; m <<= 1) {
      float ov = __shfl_xor(d, m);
      int oi = __shfl_xor(idx, m);
      if (ov > d || (ov == d && oi < idx)) {
        d = ov;
        idx = oi;
      }
    }
    if (l == 0) {
      unsigned u = __float_as_uint(d);
      u = ((int)u < 0) ? ~u : (u | 0x80000000u);
      unsigned long long key = ((unsigned long long)u << 32) | (unsigned)(~idx);
      atomicMax(keys + p, key);
    }
  }
}

// ---- gather: Nh = fp16(queue[idx]); diag = dot(nn, p_other) exact fp32 ----
__global__ __launch_bounds__(256) void k_gather(const float* __restrict__ queue,
                                                const float* __restrict__ in1,
                                                const float* __restrict__ in2,
                                                const unsigned long long* __restrict__ keys,
                                                _Float16* __restrict__ Nh,
                                                float* __restrict__ diag) {
  int t = threadIdx.x, w = t >> 6, l = t & 63;
  int g = blockIdx.x * 4 + w;  // 0..8191
  int view = g >> 12, row = g & (B_N - 1);
  unsigned long long key = keys[g];
  int qidx = (int)(~(unsigned)(key & 0xffffffffull));
  const float* q = queue + (size_t)qidx * D_N;
  float2 qv = *(const float2*)(q + 2 * l);
  *(fp16x2*)(Nh + (size_t)g * D_N + 2 * l) = __builtin_amdgcn_cvt_pkrtz(qv.x, qv.y);
  const float* oth = (view ? in1 : in2) + (size_t)row * D_N;
  float2 ov = *(const float2*)(oth + 2 * l);
  float ss = fmaf(ov.x, ov.x, ov.y * ov.y);
  float d = fmaf(qv.x, ov.x, qv.y * ov.y);
#pragma unroll
  for (int m = 1; m < 64; m <<= 1) {
    ss += __shfl_xor(ss, m);
    d += __shfl_xor(d, m);
  }
  if (l == 0) diag[g] = d / sqrtf(ss);
}

// ---- loss GEMM: LDS-staged B tiles + stationary A frags + fixed-shift LSE ----
__global__ __launch_bounds__(256, 2) void k_loss(const _Float16* __restrict__ Ph,
                                                 const _Float16* __restrict__ Nh,
                                                 float* __restrict__ Spart) {
  __shared__ _Float16 sm[2][16384];
  __shared__ float sred[2][2][64];
  int rb = blockIdx.x;     // 0..127
  int chunk = blockIdx.y;  // 0..3
  int pair = rb >> 5, rowblk = rb & 31;
  const size_t BDh = (size_t)B_N * D_N;
  const _Float16* A = (pair == 0) ? Nh : (pair == 1) ? (Ph + BDh) : (pair == 2) ? (Nh + BDh) : Ph;
  const _Float16* Bm = (pair == 0) ? (Ph + BDh) : (pair == 1) ? Nh : (pair == 2) ? Ph : (Nh + BDh);
  int t = threadIdx.x, l = t & 63, w = t >> 6;
  int wr = w >> 1, wc = w & 1, l15 = l & 15, l4 = l >> 4;
  half8 Af[4][4];
  const _Float16* ab = A + (size_t)(rowblk * 128 + wr * 64 + l15) * D_N + l4 * 8;
#pragma unroll
  for (int ti = 0; ti < 4; ++ti)
#pragma unroll
    for (int ks = 0; ks < 4; ++ks)
      Af[ti][ks] = *(const half8*)(ab + (size_t)ti * 16 * D_N + ks * 32);
  float S[16];
#pragma unroll
  for (int i = 0; i < 16; ++i) S[i] = 0.f;
  // prologue stage ct=0
  {
    int crow0 = chunk * 1024;
#pragma unroll
    for (int j = 0; j < 8; ++j) {
      int r = ((w * 8 + j) << 2) + l4;
      const _Float16* src = Bm + ((size_t)(crow0 + r) << 7) + ((l15 ^ (r & 7)) << 3);
      gload16(src, (char*)(&sm[0][0]) + ((w * 8 + j) << 10));
    }
  }
#pragma unroll 1
  for (int ct = 0; ct < 8; ++ct) {
    int cur = ct & 1;
    __syncthreads();
    if (ct + 1 < 8) {
      int crow0 = chunk * 1024 + (ct + 1) * 128;
#pragma unroll
      for (int j = 0; j < 8; ++j) {
        int r = ((w * 8 + j) << 2) + l4;
        const _Float16* src = Bm + ((size_t)(crow0 + r) << 7) + ((l15 ^ (r & 7)) << 3);
        gload16(src, (char*)(&sm[cur ^ 1][0]) + ((w * 8 + j) << 10));
      }
    }
    const char* bbp = (const char*)(&sm[cur][0]);
    f32x4 acc[4][4];
#pragma unroll
    for (int i = 0; i < 4; ++i)
#pragma unroll
      for (int j = 0; j < 4; ++j) acc[i][j] = (f32x4){0.f, 0.f, 0.f, 0.f};
#pragma unroll
    for (int ks = 0; ks < 4; ++ks) {
      half8 Bf[4];
#pragma unroll
      for (int tj = 0; tj < 4; ++tj) {
        int bloc = wc * 64 + tj * 16 + l15;
        int byteo = bloc * 256 + ((((ks << 2) + l4) ^ (bloc & 7)) << 4);
        Bf[tj] = *(const half8*)(bbp + byteo);
      }
#pragma unroll
      for (int ti = 0; ti < 4; ++ti)
#pragma unroll
        for (int tj = 0; tj < 4; ++tj)
          acc[ti][tj] =
              __builtin_amdgcn_mfma_f32_16x16x32_f16(Af[ti][ks], Bf[tj], acc[ti][tj], 0, 0, 0);
    }
#pragma unroll
    for (int ti = 0; ti < 4; ++ti)
#pragma unroll
      for (int r = 0; r < 4; ++r) {
        float e = 0.f;
#pragma unroll
        for (int tj = 0; tj < 4; ++tj) e += exp2f(fmaf(acc[ti][tj][r], C1F, -C2F));
        S[ti * 4 + r] += e;
      }
  }
#pragma unroll
  for (int i = 0; i < 16; ++i) {
#pragma unroll
    for (int m = 1; m < 16; m <<= 1) S[i] += __shfl_xor(S[i], m);
  }
  __syncthreads();
  if (l15 == 0) {
#pragma unroll
    for (int ti = 0; ti < 4; ++ti)
#pragma unroll
      for (int r = 0; r < 4; ++r) sred[wr][wc][ti * 16 + l4 * 4 + r] = S[ti * 4 + r];
  }
  __syncthreads();
  if (t < 128) {
    int wrr = t >> 6, rl = t & 63;
    float s = sred[wrr][0][rl] + sred[wrr][1][rl];
    int row = pair * B_N + rowblk * 128 + wrr * 64 + rl;
    Spart[(size_t)row * 4 + chunk] = s;
  }
}

__global__ __launch_bounds__(256) void k_merge(const float* __restrict__ Spart,
                                               const float* __restrict__ diag,
                                               float* __restrict__ out) {
  int row = blockIdx.x * 256 + threadIdx.x;  // 0..16383
  const float* sp = Spart + (size_t)row * 4;
  float s = sp[0] + sp[1] + sp[2] + sp[3];
  int pair = row >> 12, r = row & (B_N - 1);
  float dg = diag[(pair >> 1) * B_N + r];
  out[row] = logf(s) + 16.0f - INV_T * dg;
}

extern "C" void kernel_launch(void* const* d_in, const int* in_sizes, int n_in,
                              void* d_out, int out_size, void* d_ws, size_t ws_size,
                              hipStream_t stream) {
  const float* in1 = (const float*)d_in[0];
  const float* in2 = (const float*)d_in[1];
  const float* queue = (const float*)d_in[2];
  float* out = (float*)d_out;
  char* ws = (char*)d_ws;
  _Float16* Ph = (_Float16*)(ws + OFF_PH);
  _Float16* Qhh = (_Float16*)(ws + OFF_QH);
  _Float16* Nh = (_Float16*)(ws + OFF_NH);
  _Float16* TV = (_Float16*)(ws + OFF_TV);
  float* DG = (float*)(ws + OFF_DG);
  float* SP = (float*)(ws + OFF_SP);
  float* RM1 = (float*)(ws + OFF_RM1);
  float* RM = (float*)(ws + OFF_RM);
  unsigned long long* KEY = (unsigned long long*)(ws + OFF_KEY);

  hipLaunchKernelGGL(k_normalize, dim3(2048), dim3(256), 0, stream, in1, in2, Ph);
  for (int h = 0; h < 2; ++h) {
    hipLaunchKernelGGL(k_qcvt, dim3(1024), dim3(256), 0, stream, queue + (size_t)h * 16384 * D_N,
                       Qhh);
    hipLaunchKernelGGL(k_nn, dim3(512), dim3(256), 0, stream, Qhh, Ph, TV, h);
  }
  hipLaunchKernelGGL(k_rowmax1, dim3(32, 8), dim3(256), 0, stream, TV, RM1);
  hipLaunchKernelGGL(k_rowmax2, dim3(32), dim3(256), 0, stream, RM1, RM, KEY);
  hipLaunchKernelGGL(k_rescore, dim3(512), dim3(256), 0, stream, queue, in1, in2, TV, RM, KEY);
  hipLaunchKernelGGL(k_gather, dim3(2048), dim3(256), 0, stream, queue, in1, in2, KEY, Nh, DG);
  hipLaunchKernelGGL(k_loss, dim3(128, 4), dim3(256), 0, stream, Ph, Nh, SP);
  hipLaunchKernelGGL(k_merge, dim3(64), dim3(256), 0, stream, SP, DG, out);
}